// Round 1
// baseline (4318.085 us; speedup 1.0000x reference)
//
#include <hip/hip_runtime.h>
#include <hip/hip_bf16.h>

#define NN 100000
#define NE 1600000
#define DIN 512
#define DH 128
#define DOUT 64

// ---------------- GEMM1: h1[N,128] = x @ w1^T ----------------
// 64-row tile, full 128 cols, BK=32. Transposed LDS so fragment reads are b128.
__global__ __launch_bounds__(256) void gemm1_kernel(const float* __restrict__ x,
                                                    const float* __restrict__ w1,
                                                    float* __restrict__ h1) {
    __shared__ float xsT[32][68];    // [k][row], stride 68 -> 16B-aligned rows, spread banks
    __shared__ float wsT[32][132];   // [k][col]
    const int t  = threadIdx.x;
    const int bm = blockIdx.x * 64;
    const int tx = t & 15;   // cols tx*8 .. tx*8+7
    const int ty = t >> 4;   // rows ty*4 .. ty*4+3

    float acc[4][8];
#pragma unroll
    for (int i = 0; i < 4; i++)
#pragma unroll
        for (int j = 0; j < 8; j++) acc[i][j] = 0.f;

    for (int k0 = 0; k0 < DIN; k0 += 32) {
        for (int i = t; i < 512; i += 256) {          // x tile: 64 rows x 32 k
            int r = i >> 3, c4 = i & 7;
            int n = bm + r;
            float4 v = make_float4(0.f, 0.f, 0.f, 0.f);
            if (n < NN) v = *(const float4*)&x[(size_t)n * DIN + k0 + c4 * 4];
            xsT[c4 * 4 + 0][r] = v.x; xsT[c4 * 4 + 1][r] = v.y;
            xsT[c4 * 4 + 2][r] = v.z; xsT[c4 * 4 + 3][r] = v.w;
        }
        for (int i = t; i < 1024; i += 256) {         // w1 tile: 128 rows x 32 k
            int r = i >> 3, c4 = i & 7;
            float4 v = *(const float4*)&w1[(size_t)r * DIN + k0 + c4 * 4];
            wsT[c4 * 4 + 0][r] = v.x; wsT[c4 * 4 + 1][r] = v.y;
            wsT[c4 * 4 + 2][r] = v.z; wsT[c4 * 4 + 3][r] = v.w;
        }
        __syncthreads();
#pragma unroll
        for (int k = 0; k < 32; k++) {
            float4 av = *(const float4*)&xsT[k][ty * 4];
            float4 b0 = *(const float4*)&wsT[k][tx * 8];
            float4 b1 = *(const float4*)&wsT[k][tx * 8 + 4];
            float a[4] = {av.x, av.y, av.z, av.w};
            float b[8] = {b0.x, b0.y, b0.z, b0.w, b1.x, b1.y, b1.z, b1.w};
#pragma unroll
            for (int i = 0; i < 4; i++)
#pragma unroll
                for (int j = 0; j < 8; j++)
                    acc[i][j] = fmaf(a[i], b[j], acc[i][j]);
        }
        __syncthreads();
    }
#pragma unroll
    for (int i = 0; i < 4; i++) {
        int n = bm + ty * 4 + i;
        if (n < NN) {
            float4 v0 = make_float4(acc[i][0], acc[i][1], acc[i][2], acc[i][3]);
            float4 v1 = make_float4(acc[i][4], acc[i][5], acc[i][6], acc[i][7]);
            *(float4*)&h1[(size_t)n * DH + tx * 8]     = v0;
            *(float4*)&h1[(size_t)n * DH + tx * 8 + 4] = v1;
        }
    }
}

// ---------------- SpMM: out[dst] += w * h[src], atomic scatter ----------------
template <int D>
__global__ __launch_bounds__(256) void spmm_kernel(const int* __restrict__ esrc,
                                                   const int* __restrict__ edst,
                                                   const float* __restrict__ ew,
                                                   const float* __restrict__ h,
                                                   float* __restrict__ out) {
    constexpr int TPE = D / 4;                    // threads per edge (float4 each)
    long long gid = (long long)blockIdx.x * blockDim.x + threadIdx.x;
    long long e = gid / TPE;
    int d = (int)(gid % TPE) * 4;
    if (e >= NE) return;
    int s = esrc[e], dt = edst[e];
    float w = ew[e];
    float4 v = *(const float4*)&h[(size_t)s * D + d];
    float* o = &out[(size_t)dt * D + d];
    atomicAdd(o + 0, w * v.x);
    atomicAdd(o + 1, w * v.y);
    atomicAdd(o + 2, w * v.z);
    atomicAdd(o + 3, w * v.w);
}

// ---------------- GEMM2: h2[N,64] = relu(agg1) @ w2^T ----------------
// 64-row tile, K=128 fully staged, 2 rows x 8 cols per thread.
__global__ __launch_bounds__(256) void gemm2_kernel(const float* __restrict__ agg1,
                                                    const float* __restrict__ w2,
                                                    float* __restrict__ h2) {
    __shared__ float as[64][132];    // [row][k], relu applied at stage
    __shared__ float w2T[128][68];   // [k][col]
    const int t  = threadIdx.x;
    const int bm = blockIdx.x * 64;
    const int tx = t & 7;    // cols tx*8..+7
    const int ty = t >> 3;   // rows ty, ty+32

    for (int i = t; i < 2048; i += 256) {         // agg1 tile: 64 x 128
        int r = i >> 5, c4 = i & 31;
        int n = bm + r;
        float4 v = make_float4(0.f, 0.f, 0.f, 0.f);
        if (n < NN) v = *(const float4*)&agg1[(size_t)n * DH + c4 * 4];
        v.x = fmaxf(v.x, 0.f); v.y = fmaxf(v.y, 0.f);
        v.z = fmaxf(v.z, 0.f); v.w = fmaxf(v.w, 0.f);
        *(float4*)&as[r][c4 * 4] = v;
    }
    for (int i = t; i < 2048; i += 256) {         // w2: 64 x 128, transposed
        int r = i >> 5, c4 = i & 31;
        float4 v = *(const float4*)&w2[(size_t)r * DH + c4 * 4];
        w2T[c4 * 4 + 0][r] = v.x; w2T[c4 * 4 + 1][r] = v.y;
        w2T[c4 * 4 + 2][r] = v.z; w2T[c4 * 4 + 3][r] = v.w;
    }
    __syncthreads();

    float acc[2][8];
#pragma unroll
    for (int i = 0; i < 2; i++)
#pragma unroll
        for (int j = 0; j < 8; j++) acc[i][j] = 0.f;

#pragma unroll 8
    for (int k = 0; k < DH; k++) {
        float a0 = as[ty][k];
        float a1 = as[ty + 32][k];
        float4 b0 = *(const float4*)&w2T[k][tx * 8];
        float4 b1 = *(const float4*)&w2T[k][tx * 8 + 4];
        float b[8] = {b0.x, b0.y, b0.z, b0.w, b1.x, b1.y, b1.z, b1.w};
#pragma unroll
        for (int j = 0; j < 8; j++) {
            acc[0][j] = fmaf(a0, b[j], acc[0][j]);
            acc[1][j] = fmaf(a1, b[j], acc[1][j]);
        }
    }
#pragma unroll
    for (int i = 0; i < 2; i++) {
        int n = bm + ty + i * 32;
        if (n < NN) {
            float4 v0 = make_float4(acc[i][0], acc[i][1], acc[i][2], acc[i][3]);
            float4 v1 = make_float4(acc[i][4], acc[i][5], acc[i][6], acc[i][7]);
            *(float4*)&h2[(size_t)n * DOUT + tx * 8]     = v0;
            *(float4*)&h2[(size_t)n * DOUT + tx * 8 + 4] = v1;
        }
    }
}

// ---------------- log_softmax over 64 cols, one wave per row, in-place ----------------
__global__ __launch_bounds__(256) void logsoftmax_kernel(float* __restrict__ io) {
    int wid  = (int)((blockIdx.x * (long long)blockDim.x + threadIdx.x) >> 6);
    int lane = threadIdx.x & 63;
    if (wid >= NN) return;
    float v = io[(size_t)wid * 64 + lane];
    float m = v;
#pragma unroll
    for (int off = 32; off >= 1; off >>= 1) m = fmaxf(m, __shfl_xor(m, off));
    float ex = expf(v - m);
    float s = ex;
#pragma unroll
    for (int off = 32; off >= 1; off >>= 1) s += __shfl_xor(s, off);
    io[(size_t)wid * 64 + lane] = (v - m) - logf(s);
}

extern "C" void kernel_launch(void* const* d_in, const int* in_sizes, int n_in,
                              void* d_out, int out_size, void* d_ws, size_t ws_size,
                              hipStream_t stream) {
    const float* x  = (const float*)d_in[0];
    const float* w1 = (const float*)d_in[1];
    const float* w2 = (const float*)d_in[2];
    const int* esrc = (const int*)d_in[3];
    const int* edst = (const int*)d_in[4];
    const float* ew = (const float*)d_in[5];
    float* out = (float*)d_out;

    char* ws = (char*)d_ws;
    float* h1   = (float*)(ws);                             // N*128 f32 (51.2 MB)
    float* agg1 = (float*)(ws + (size_t)NN * DH * 4);       // N*128 f32 (51.2 MB)
    float* h2   = (float*)(ws);                             // N*64 f32, reuses h1 region

    // 1. h1 = x @ w1^T
    gemm1_kernel<<<(NN + 63) / 64, 256, 0, stream>>>(x, w1, h1);
    // 2. agg1 = scatter_add(w * h1[src] -> dst)
    hipMemsetAsync(agg1, 0, (size_t)NN * DH * 4, stream);
    spmm_kernel<DH><<<(NE * (DH / 4) + 255) / 256, 256, 0, stream>>>(esrc, edst, ew, h1, agg1);
    // 3. h2 = relu(agg1) @ w2^T
    gemm2_kernel<<<(NN + 63) / 64, 256, 0, stream>>>(agg1, w2, h2);
    // 4. out = scatter_add(w * h2[src] -> dst)
    hipMemsetAsync(out, 0, (size_t)NN * DOUT * 4, stream);
    spmm_kernel<DOUT><<<(NE * (DOUT / 4) + 255) / 256, 256, 0, stream>>>(esrc, edst, ew, h2, out);
    // 5. in-place log_softmax
    logsoftmax_kernel<<<(NN * 64) / 256, 256, 0, stream>>>(out);
}

// Round 2
// 662.669 us; speedup vs baseline: 6.5162x; 6.5162x over previous
//
#include <hip/hip_runtime.h>
#include <hip/hip_bf16.h>

#define NN 100000
#define NE 1600000
#define DIN 512
#define DH 128
#define DOUT 64
#define NCH ((NN + 255) / 256)   // 391 chunks for the scan

// ---------------- GEMM1: h1[N,128] = x @ w1^T ----------------
__global__ __launch_bounds__(256) void gemm1_kernel(const float* __restrict__ x,
                                                    const float* __restrict__ w1,
                                                    float* __restrict__ h1) {
    __shared__ float xsT[32][68];
    __shared__ float wsT[32][132];
    const int t  = threadIdx.x;
    const int bm = blockIdx.x * 64;
    const int tx = t & 15;
    const int ty = t >> 4;

    float acc[4][8];
#pragma unroll
    for (int i = 0; i < 4; i++)
#pragma unroll
        for (int j = 0; j < 8; j++) acc[i][j] = 0.f;

    for (int k0 = 0; k0 < DIN; k0 += 32) {
        for (int i = t; i < 512; i += 256) {
            int r = i >> 3, c4 = i & 7;
            int n = bm + r;
            float4 v = make_float4(0.f, 0.f, 0.f, 0.f);
            if (n < NN) v = *(const float4*)&x[(size_t)n * DIN + k0 + c4 * 4];
            xsT[c4 * 4 + 0][r] = v.x; xsT[c4 * 4 + 1][r] = v.y;
            xsT[c4 * 4 + 2][r] = v.z; xsT[c4 * 4 + 3][r] = v.w;
        }
        for (int i = t; i < 1024; i += 256) {
            int r = i >> 3, c4 = i & 7;
            float4 v = *(const float4*)&w1[(size_t)r * DIN + k0 + c4 * 4];
            wsT[c4 * 4 + 0][r] = v.x; wsT[c4 * 4 + 1][r] = v.y;
            wsT[c4 * 4 + 2][r] = v.z; wsT[c4 * 4 + 3][r] = v.w;
        }
        __syncthreads();
#pragma unroll
        for (int k = 0; k < 32; k++) {
            float4 av = *(const float4*)&xsT[k][ty * 4];
            float4 b0 = *(const float4*)&wsT[k][tx * 8];
            float4 b1 = *(const float4*)&wsT[k][tx * 8 + 4];
            float a[4] = {av.x, av.y, av.z, av.w};
            float b[8] = {b0.x, b0.y, b0.z, b0.w, b1.x, b1.y, b1.z, b1.w};
#pragma unroll
            for (int i = 0; i < 4; i++)
#pragma unroll
                for (int j = 0; j < 8; j++)
                    acc[i][j] = fmaf(a[i], b[j], acc[i][j]);
        }
        __syncthreads();
    }
#pragma unroll
    for (int i = 0; i < 4; i++) {
        int n = bm + ty * 4 + i;
        if (n < NN) {
            float4 v0 = make_float4(acc[i][0], acc[i][1], acc[i][2], acc[i][3]);
            float4 v1 = make_float4(acc[i][4], acc[i][5], acc[i][6], acc[i][7]);
            *(float4*)&h1[(size_t)n * DH + tx * 8]     = v0;
            *(float4*)&h1[(size_t)n * DH + tx * 8 + 4] = v1;
        }
    }
}

// ---------------- CSR build ----------------
__global__ __launch_bounds__(256) void hist_kernel(const int* __restrict__ edst,
                                                   int* __restrict__ deg) {
    int e = blockIdx.x * 256 + threadIdx.x;
    if (e < NE) atomicAdd(&deg[edst[e]], 1);
}

__global__ __launch_bounds__(256) void chunksum_kernel(const int* __restrict__ deg,
                                                       int* __restrict__ csum) {
    __shared__ int sm[256];
    int c = blockIdx.x, t = threadIdx.x, n = c * 256 + t;
    sm[t] = (n < NN) ? deg[n] : 0;
    __syncthreads();
#pragma unroll
    for (int off = 128; off >= 1; off >>= 1) {
        if (t < off) sm[t] += sm[t + off];
        __syncthreads();
    }
    if (t == 0) csum[c] = sm[0];
}

__global__ __launch_bounds__(512) void scanchunks_kernel(const int* __restrict__ csum,
                                                         int* __restrict__ cbase,
                                                         int* __restrict__ rowptr) {
    __shared__ int sm[512];
    int t = threadIdx.x;
    int self = (t < NCH) ? csum[t] : 0;
    sm[t] = self;
    __syncthreads();
    for (int off = 1; off < 512; off <<= 1) {
        int v = (t >= off) ? sm[t - off] : 0;
        __syncthreads();
        sm[t] += v;
        __syncthreads();
    }
    if (t < NCH) cbase[t] = sm[t] - self;   // exclusive chunk base
    if (t == 0) rowptr[NN] = NE;
}

__global__ __launch_bounds__(256) void scanwrite_kernel(const int* __restrict__ deg,
                                                        const int* __restrict__ cbase,
                                                        int* __restrict__ rowptr,
                                                        int* __restrict__ cursor) {
    __shared__ int sm[256];
    int c = blockIdx.x, t = threadIdx.x, n = c * 256 + t;
    int d = (n < NN) ? deg[n] : 0;
    sm[t] = d;
    __syncthreads();
#pragma unroll
    for (int off = 1; off < 256; off <<= 1) {
        int v = (t >= off) ? sm[t - off] : 0;
        __syncthreads();
        sm[t] += v;
        __syncthreads();
    }
    if (n < NN) {
        int rp = cbase[c] + sm[t] - d;
        rowptr[n] = rp;
        cursor[n] = rp;
    }
}

__global__ __launch_bounds__(256) void scatter_kernel(const int* __restrict__ esrc,
                                                      const int* __restrict__ edst,
                                                      const float* __restrict__ ew,
                                                      int* __restrict__ cursor,
                                                      int2* __restrict__ csr) {
    int e = blockIdx.x * 256 + threadIdx.x;
    if (e >= NE) return;
    int dt = edst[e];
    int pos = atomicAdd(&cursor[dt], 1);
    csr[pos] = make_int2(esrc[e], __float_as_int(ew[e]));
}

// ---------------- SpMM-CSR d=128: wave per node, gather, no atomics ----------------
__global__ __launch_bounds__(256) void spmm_csr128_kernel(const int2* __restrict__ csr,
                                                          const int* __restrict__ rowptr,
                                                          const float* __restrict__ h,
                                                          float* __restrict__ outp) {
    int n = blockIdx.x * 4 + (threadIdx.x >> 6);
    int lane = threadIdx.x & 63;
    if (n >= NN) return;
    int i = rowptr[n], end = rowptr[n + 1];
    float2 acc = make_float2(0.f, 0.f);
    for (; i + 1 < end; i += 2) {
        int2 e0 = csr[i];
        int2 e1 = csr[i + 1];
        float2 v0 = *(const float2*)&h[(size_t)e0.x * DH + lane * 2];
        float2 v1 = *(const float2*)&h[(size_t)e1.x * DH + lane * 2];
        float w0 = __int_as_float(e0.y), w1 = __int_as_float(e1.y);
        acc.x = fmaf(w0, v0.x, acc.x); acc.y = fmaf(w0, v0.y, acc.y);
        acc.x = fmaf(w1, v1.x, acc.x); acc.y = fmaf(w1, v1.y, acc.y);
    }
    if (i < end) {
        int2 e0 = csr[i];
        float2 v0 = *(const float2*)&h[(size_t)e0.x * DH + lane * 2];
        float w0 = __int_as_float(e0.y);
        acc.x = fmaf(w0, v0.x, acc.x); acc.y = fmaf(w0, v0.y, acc.y);
    }
    *(float2*)&outp[(size_t)n * DH + lane * 2] = acc;
}

// ---------------- SpMM-CSR d=64 + fused log_softmax ----------------
__global__ __launch_bounds__(256) void spmm_csr64_ls_kernel(const int2* __restrict__ csr,
                                                            const int* __restrict__ rowptr,
                                                            const float* __restrict__ h,
                                                            float* __restrict__ outp) {
    int n = blockIdx.x * 4 + (threadIdx.x >> 6);
    int lane = threadIdx.x & 63;
    if (n >= NN) return;
    int i = rowptr[n], end = rowptr[n + 1];
    float acc = 0.f;
    for (; i + 1 < end; i += 2) {
        int2 e0 = csr[i];
        int2 e1 = csr[i + 1];
        float v0 = h[(size_t)e0.x * DOUT + lane];
        float v1 = h[(size_t)e1.x * DOUT + lane];
        acc = fmaf(__int_as_float(e0.y), v0, acc);
        acc = fmaf(__int_as_float(e1.y), v1, acc);
    }
    if (i < end) {
        int2 e0 = csr[i];
        acc = fmaf(__int_as_float(e0.y), h[(size_t)e0.x * DOUT + lane], acc);
    }
    // fused log_softmax across the 64-lane row
    float m = acc;
#pragma unroll
    for (int off = 32; off >= 1; off >>= 1) m = fmaxf(m, __shfl_xor(m, off));
    float ex = expf(acc - m);
    float s = ex;
#pragma unroll
    for (int off = 32; off >= 1; off >>= 1) s += __shfl_xor(s, off);
    outp[(size_t)n * DOUT + lane] = (acc - m) - logf(s);
}

// ---------------- GEMM2: h2[N,64] = relu(agg1) @ w2^T ----------------
__global__ __launch_bounds__(256) void gemm2_kernel(const float* __restrict__ agg1,
                                                    const float* __restrict__ w2,
                                                    float* __restrict__ h2) {
    __shared__ float as[64][132];
    __shared__ float w2T[128][68];
    const int t  = threadIdx.x;
    const int bm = blockIdx.x * 64;
    const int tx = t & 7;
    const int ty = t >> 3;

    for (int i = t; i < 2048; i += 256) {
        int r = i >> 5, c4 = i & 31;
        int n = bm + r;
        float4 v = make_float4(0.f, 0.f, 0.f, 0.f);
        if (n < NN) v = *(const float4*)&agg1[(size_t)n * DH + c4 * 4];
        v.x = fmaxf(v.x, 0.f); v.y = fmaxf(v.y, 0.f);
        v.z = fmaxf(v.z, 0.f); v.w = fmaxf(v.w, 0.f);
        *(float4*)&as[r][c4 * 4] = v;
    }
    for (int i = t; i < 2048; i += 256) {
        int r = i >> 5, c4 = i & 31;
        float4 v = *(const float4*)&w2[(size_t)r * DH + c4 * 4];
        w2T[c4 * 4 + 0][r] = v.x; w2T[c4 * 4 + 1][r] = v.y;
        w2T[c4 * 4 + 2][r] = v.z; w2T[c4 * 4 + 3][r] = v.w;
    }
    __syncthreads();

    float acc[2][8];
#pragma unroll
    for (int i = 0; i < 2; i++)
#pragma unroll
        for (int j = 0; j < 8; j++) acc[i][j] = 0.f;

#pragma unroll 8
    for (int k = 0; k < DH; k++) {
        float a0 = as[ty][k];
        float a1 = as[ty + 32][k];
        float4 b0 = *(const float4*)&w2T[k][tx * 8];
        float4 b1 = *(const float4*)&w2T[k][tx * 8 + 4];
        float b[8] = {b0.x, b0.y, b0.z, b0.w, b1.x, b1.y, b1.z, b1.w};
#pragma unroll
        for (int j = 0; j < 8; j++) {
            acc[0][j] = fmaf(a0, b[j], acc[0][j]);
            acc[1][j] = fmaf(a1, b[j], acc[1][j]);
        }
    }
#pragma unroll
    for (int i = 0; i < 2; i++) {
        int n = bm + ty + i * 32;
        if (n < NN) {
            float4 v0 = make_float4(acc[i][0], acc[i][1], acc[i][2], acc[i][3]);
            float4 v1 = make_float4(acc[i][4], acc[i][5], acc[i][6], acc[i][7]);
            *(float4*)&h2[(size_t)n * DOUT + tx * 8]     = v0;
            *(float4*)&h2[(size_t)n * DOUT + tx * 8 + 4] = v1;
        }
    }
}

// ---------------- fallback atomic SpMM (used only if ws is too small) ----------------
template <int D>
__global__ __launch_bounds__(256) void spmm_atomic_kernel(const int* __restrict__ esrc,
                                                          const int* __restrict__ edst,
                                                          const float* __restrict__ ew,
                                                          const float* __restrict__ h,
                                                          float* __restrict__ out) {
    constexpr int TPE = D / 4;
    long long gid = (long long)blockIdx.x * blockDim.x + threadIdx.x;
    long long e = gid / TPE;
    int d = (int)(gid % TPE) * 4;
    if (e >= NE) return;
    int s = esrc[e], dt = edst[e];
    float w = ew[e];
    float4 v = *(const float4*)&h[(size_t)s * D + d];
    float* o = &out[(size_t)dt * D + d];
    atomicAdd(o + 0, w * v.x);
    atomicAdd(o + 1, w * v.y);
    atomicAdd(o + 2, w * v.z);
    atomicAdd(o + 3, w * v.w);
}

__global__ __launch_bounds__(256) void logsoftmax_kernel(float* __restrict__ io) {
    int wid  = (int)((blockIdx.x * (long long)blockDim.x + threadIdx.x) >> 6);
    int lane = threadIdx.x & 63;
    if (wid >= NN) return;
    float v = io[(size_t)wid * 64 + lane];
    float m = v;
#pragma unroll
    for (int off = 32; off >= 1; off >>= 1) m = fmaxf(m, __shfl_xor(m, off));
    float ex = expf(v - m);
    float s = ex;
#pragma unroll
    for (int off = 32; off >= 1; off >>= 1) s += __shfl_xor(s, off);
    io[(size_t)wid * 64 + lane] = (v - m) - logf(s);
}

extern "C" void kernel_launch(void* const* d_in, const int* in_sizes, int n_in,
                              void* d_out, int out_size, void* d_ws, size_t ws_size,
                              hipStream_t stream) {
    const float* x  = (const float*)d_in[0];
    const float* w1 = (const float*)d_in[1];
    const float* w2 = (const float*)d_in[2];
    const int* esrc = (const int*)d_in[3];
    const int* edst = (const int*)d_in[4];
    const float* ew = (const float*)d_in[5];
    float* out = (float*)d_out;

    char* ws = (char*)d_ws;
    size_t off = 0;
    auto alloc = [&](size_t bytes) {
        void* p = ws + off;
        off = (off + bytes + 255) & ~(size_t)255;
        return p;
    };
    float* h1     = (float*)alloc((size_t)NN * DH * 4);      // 51.2 MB (h2 reuses)
    float* agg1   = (float*)alloc((size_t)NN * DH * 4);      // 51.2 MB
    size_t base_needed = off;
    int2*  csr    = (int2*)alloc((size_t)NE * 8);            // 12.8 MB
    int*   rowptr = (int*)alloc((size_t)(NN + 1) * 4);
    int*   cursor = (int*)alloc((size_t)NN * 4);
    int*   deg    = (int*)alloc((size_t)NN * 4);
    int*   csum   = (int*)alloc((size_t)NCH * 4);
    int*   cbase  = (int*)alloc((size_t)NCH * 4);
    size_t csr_needed = off;
    float* h2 = h1;

    bool use_csr = (ws_size >= csr_needed);

    // 1. h1 = x @ w1^T
    gemm1_kernel<<<(NN + 63) / 64, 256, 0, stream>>>(x, w1, h1);

    if (use_csr) {
        // 2. CSR build (bucket sort by dst), reused for both SpMMs
        hipMemsetAsync(deg, 0, (size_t)NN * 4, stream);
        hist_kernel<<<(NE + 255) / 256, 256, 0, stream>>>(edst, deg);
        chunksum_kernel<<<NCH, 256, 0, stream>>>(deg, csum);
        scanchunks_kernel<<<1, 512, 0, stream>>>(csum, cbase, rowptr);
        scanwrite_kernel<<<NCH, 256, 0, stream>>>(deg, cbase, rowptr, cursor);
        scatter_kernel<<<(NE + 255) / 256, 256, 0, stream>>>(esrc, edst, ew, cursor, csr);

        // 3. agg1 = gather-SpMM(h1)
        spmm_csr128_kernel<<<(NN + 3) / 4, 256, 0, stream>>>(csr, rowptr, h1, agg1);
        // 4. h2 = relu(agg1) @ w2^T
        gemm2_kernel<<<(NN + 63) / 64, 256, 0, stream>>>(agg1, w2, h2);
        // 5. out = log_softmax(gather-SpMM(h2))  (fused)
        spmm_csr64_ls_kernel<<<(NN + 3) / 4, 256, 0, stream>>>(csr, rowptr, h2, out);
    } else if (ws_size >= base_needed) {
        hipMemsetAsync(agg1, 0, (size_t)NN * DH * 4, stream);
        spmm_atomic_kernel<DH><<<(NE * (DH / 4) + 255) / 256, 256, 0, stream>>>(esrc, edst, ew, h1, agg1);
        gemm2_kernel<<<(NN + 63) / 64, 256, 0, stream>>>(agg1, w2, h2);
        hipMemsetAsync(out, 0, (size_t)NN * DOUT * 4, stream);
        spmm_atomic_kernel<DOUT><<<(NE * (DOUT / 4) + 255) / 256, 256, 0, stream>>>(esrc, edst, ew, h2, out);
        logsoftmax_kernel<<<(NN * 64) / 256, 256, 0, stream>>>(out);
    }
}

// Round 3
// 488.239 us; speedup vs baseline: 8.8442x; 1.3573x over previous
//
#include <hip/hip_runtime.h>
#include <hip/hip_bf16.h>

#define NN 100000
#define NE 1600000
#define DIN 512
#define DH 128
#define DOUT 64
#define NCH ((NN + 255) / 256)

typedef __bf16 bf16_t;
typedef __bf16 bf16x8 __attribute__((ext_vector_type(8)));
typedef float f32x4 __attribute__((ext_vector_type(4)));

__device__ __forceinline__ float bflo(unsigned v) { return __int_as_float(v << 16); }
__device__ __forceinline__ float bfhi(unsigned v) { return __int_as_float(v & 0xffff0000u); }
__device__ __forceinline__ unsigned packbf2(float a, float b) {
    unsigned short ua = __builtin_bit_cast(unsigned short, (bf16_t)a);
    unsigned short ub = __builtin_bit_cast(unsigned short, (bf16_t)b);
    return (unsigned)ua | ((unsigned)ub << 16);
}

// ---------------- weight conversion fp32 -> bf16 ----------------
__global__ __launch_bounds__(256) void convert_w_kernel(const float* __restrict__ w1,
                                                        const float* __restrict__ w2,
                                                        bf16_t* __restrict__ w1b,
                                                        bf16_t* __restrict__ w2b) {
    int i = blockIdx.x * 256 + threadIdx.x;
    if (i < DH * DIN) w1b[i] = (bf16_t)w1[i];
    if (i < DOUT * DH) w2b[i] = (bf16_t)w2[i];
}

// ---------------- GEMM1: h1b[N,128] = bf16(x) @ bf16(w1)^T, MFMA, no LDS ----------------
// 4 waves/block, 32 rows/wave (BM=128). B (w1b, 128KB) read from L2 per K-step.
__global__ __launch_bounds__(256) void gemm1_mfma(const float* __restrict__ x,
                                                  const bf16_t* __restrict__ w1b,
                                                  bf16_t* __restrict__ h1b) {
    const int t = threadIdx.x;
    const int wv = t >> 6, lane = t & 63;
    const int fr = lane & 15, fq = lane >> 4;
    const int rbase = blockIdx.x * 128 + wv * 32;

    f32x4 acc[2][8];
#pragma unroll
    for (int m = 0; m < 2; m++)
#pragma unroll
        for (int n = 0; n < 8; n++) acc[m][n] = (f32x4)0.f;

    int r0 = rbase + fr;
    int r1 = rbase + 16 + fr;
    int r0c = r0 < NN ? r0 : NN - 1;
    int r1c = r1 < NN ? r1 : NN - 1;
    const float*  pa0 = x + (size_t)r0c * DIN + fq * 8;
    const float*  pa1 = x + (size_t)r1c * DIN + fq * 8;
    const bf16_t* pb  = w1b + (size_t)fr * DIN + fq * 8;

    for (int kk = 0; kk < DIN / 32; kk++) {
        float4 a0l = *(const float4*)(pa0);
        float4 a0h = *(const float4*)(pa0 + 4);
        float4 a1l = *(const float4*)(pa1);
        float4 a1h = *(const float4*)(pa1 + 4);
        bf16x8 af0, af1;
        af0[0] = (bf16_t)a0l.x; af0[1] = (bf16_t)a0l.y; af0[2] = (bf16_t)a0l.z; af0[3] = (bf16_t)a0l.w;
        af0[4] = (bf16_t)a0h.x; af0[5] = (bf16_t)a0h.y; af0[6] = (bf16_t)a0h.z; af0[7] = (bf16_t)a0h.w;
        af1[0] = (bf16_t)a1l.x; af1[1] = (bf16_t)a1l.y; af1[2] = (bf16_t)a1l.z; af1[3] = (bf16_t)a1l.w;
        af1[4] = (bf16_t)a1h.x; af1[5] = (bf16_t)a1h.y; af1[6] = (bf16_t)a1h.z; af1[7] = (bf16_t)a1h.w;

        bf16x8 bfr[8];
#pragma unroll
        for (int n = 0; n < 8; n++)
            bfr[n] = *(const bf16x8*)(pb + (size_t)n * 16 * DIN);
#pragma unroll
        for (int n = 0; n < 8; n++) {
            acc[0][n] = __builtin_amdgcn_mfma_f32_16x16x32_bf16(af0, bfr[n], acc[0][n], 0, 0, 0);
            acc[1][n] = __builtin_amdgcn_mfma_f32_16x16x32_bf16(af1, bfr[n], acc[1][n], 0, 0, 0);
        }
        pa0 += 32; pa1 += 32; pb += 32;
    }
#pragma unroll
    for (int m = 0; m < 2; m++)
#pragma unroll
        for (int j = 0; j < 4; j++) {
            int row = rbase + m * 16 + fq * 4 + j;
            if (row < NN) {
#pragma unroll
                for (int n = 0; n < 8; n++)
                    h1b[(size_t)row * DH + n * 16 + fr] = (bf16_t)acc[m][n][j];
            }
        }
}

// ---------------- GEMM2: h2b[N,64] = agg1b(relu'd) @ bf16(w2)^T, MFMA ----------------
__global__ __launch_bounds__(256) void gemm2_mfma(const bf16_t* __restrict__ ab,
                                                  const bf16_t* __restrict__ w2b,
                                                  bf16_t* __restrict__ h2b) {
    const int t = threadIdx.x;
    const int wv = t >> 6, lane = t & 63;
    const int fr = lane & 15, fq = lane >> 4;
    const int rbase = blockIdx.x * 128 + wv * 32;

    f32x4 acc[2][4];
#pragma unroll
    for (int m = 0; m < 2; m++)
#pragma unroll
        for (int n = 0; n < 4; n++) acc[m][n] = (f32x4)0.f;

    int r0 = rbase + fr;
    int r1 = rbase + 16 + fr;
    int r0c = r0 < NN ? r0 : NN - 1;
    int r1c = r1 < NN ? r1 : NN - 1;
    const bf16_t* pa0 = ab + (size_t)r0c * DH + fq * 8;
    const bf16_t* pa1 = ab + (size_t)r1c * DH + fq * 8;
    const bf16_t* pb  = w2b + (size_t)fr * DH + fq * 8;

#pragma unroll
    for (int kk = 0; kk < DH / 32; kk++) {
        bf16x8 af0 = *(const bf16x8*)(pa0);
        bf16x8 af1 = *(const bf16x8*)(pa1);
        bf16x8 bfr[4];
#pragma unroll
        for (int n = 0; n < 4; n++)
            bfr[n] = *(const bf16x8*)(pb + (size_t)n * 16 * DH);
#pragma unroll
        for (int n = 0; n < 4; n++) {
            acc[0][n] = __builtin_amdgcn_mfma_f32_16x16x32_bf16(af0, bfr[n], acc[0][n], 0, 0, 0);
            acc[1][n] = __builtin_amdgcn_mfma_f32_16x16x32_bf16(af1, bfr[n], acc[1][n], 0, 0, 0);
        }
        pa0 += 32; pa1 += 32; pb += 32;
    }
#pragma unroll
    for (int m = 0; m < 2; m++)
#pragma unroll
        for (int j = 0; j < 4; j++) {
            int row = rbase + m * 16 + fq * 4 + j;
            if (row < NN) {
#pragma unroll
                for (int n = 0; n < 4; n++)
                    h2b[(size_t)row * DOUT + n * 16 + fr] = (bf16_t)acc[m][n][j];
            }
        }
}

// ---------------- CSR build ----------------
__global__ __launch_bounds__(256) void hist_kernel(const int* __restrict__ edst,
                                                   int* __restrict__ deg) {
    int e = blockIdx.x * 256 + threadIdx.x;
    if (e < NE) atomicAdd(&deg[edst[e]], 1);
}

__global__ __launch_bounds__(256) void chunksum_kernel(const int* __restrict__ deg,
                                                       int* __restrict__ csum) {
    __shared__ int sm[256];
    int c = blockIdx.x, t = threadIdx.x, n = c * 256 + t;
    sm[t] = (n < NN) ? deg[n] : 0;
    __syncthreads();
#pragma unroll
    for (int off = 128; off >= 1; off >>= 1) {
        if (t < off) sm[t] += sm[t + off];
        __syncthreads();
    }
    if (t == 0) csum[c] = sm[0];
}

__global__ __launch_bounds__(512) void scanchunks_kernel(const int* __restrict__ csum,
                                                         int* __restrict__ cbase,
                                                         int* __restrict__ rowptr) {
    __shared__ int sm[512];
    int t = threadIdx.x;
    int self = (t < NCH) ? csum[t] : 0;
    sm[t] = self;
    __syncthreads();
    for (int off = 1; off < 512; off <<= 1) {
        int v = (t >= off) ? sm[t - off] : 0;
        __syncthreads();
        sm[t] += v;
        __syncthreads();
    }
    if (t < NCH) cbase[t] = sm[t] - self;
    if (t == 0) rowptr[NN] = NE;
}

__global__ __launch_bounds__(256) void scanwrite_kernel(const int* __restrict__ deg,
                                                        const int* __restrict__ cbase,
                                                        int* __restrict__ rowptr,
                                                        int* __restrict__ cursor) {
    __shared__ int sm[256];
    int c = blockIdx.x, t = threadIdx.x, n = c * 256 + t;
    int d = (n < NN) ? deg[n] : 0;
    sm[t] = d;
    __syncthreads();
#pragma unroll
    for (int off = 1; off < 256; off <<= 1) {
        int v = (t >= off) ? sm[t - off] : 0;
        __syncthreads();
        sm[t] += v;
        __syncthreads();
    }
    if (n < NN) {
        int rp = cbase[c] + sm[t] - d;
        rowptr[n] = rp;
        cursor[n] = rp;
    }
}

__global__ __launch_bounds__(256) void scatter_kernel(const int* __restrict__ esrc,
                                                      const int* __restrict__ edst,
                                                      const float* __restrict__ ew,
                                                      int* __restrict__ cursor,
                                                      int2* __restrict__ csr) {
    int e = blockIdx.x * 256 + threadIdx.x;
    if (e >= NE) return;
    int dt = edst[e];
    int pos = atomicAdd(&cursor[dt], 1);
    csr[pos] = make_int2(esrc[e], __float_as_int(ew[e]));
}

// ---------------- SpMM-CSR d=128 (bf16 gather, fp32 acc, fused relu, bf16 store) ----------------
__global__ __launch_bounds__(256) void spmm128_kernel(const int2* __restrict__ csr,
                                                      const int* __restrict__ rowptr,
                                                      const bf16_t* __restrict__ h1b,
                                                      bf16_t* __restrict__ aggb) {
    int n = blockIdx.x * 4 + (threadIdx.x >> 6);
    int lane = threadIdx.x & 63;
    if (n >= NN) return;
    int i = rowptr[n], end = rowptr[n + 1];
    float ax = 0.f, ay = 0.f;
    for (; i + 1 < end; i += 2) {
        int2 e0 = csr[i];
        int2 e1 = csr[i + 1];
        unsigned v0 = *(const unsigned*)&h1b[(size_t)e0.x * DH + lane * 2];
        unsigned v1 = *(const unsigned*)&h1b[(size_t)e1.x * DH + lane * 2];
        float w0 = __int_as_float(e0.y), w1 = __int_as_float(e1.y);
        ax = fmaf(w0, bflo(v0), ax); ay = fmaf(w0, bfhi(v0), ay);
        ax = fmaf(w1, bflo(v1), ax); ay = fmaf(w1, bfhi(v1), ay);
    }
    if (i < end) {
        int2 e0 = csr[i];
        unsigned v0 = *(const unsigned*)&h1b[(size_t)e0.x * DH + lane * 2];
        float w0 = __int_as_float(e0.y);
        ax = fmaf(w0, bflo(v0), ax); ay = fmaf(w0, bfhi(v0), ay);
    }
    ax = fmaxf(ax, 0.f); ay = fmaxf(ay, 0.f);   // fused relu
    *(unsigned*)&aggb[(size_t)n * DH + lane * 2] = packbf2(ax, ay);
}

// ---------------- SpMM-CSR d=64 + fused log_softmax (2 edges/iter, half-wave each) ----------------
__global__ __launch_bounds__(256) void spmm64_ls_kernel(const int2* __restrict__ csr,
                                                        const int* __restrict__ rowptr,
                                                        const bf16_t* __restrict__ h2b,
                                                        float* __restrict__ outp) {
    int n = blockIdx.x * 4 + (threadIdx.x >> 6);
    int lane = threadIdx.x & 63;
    int half = lane >> 5, lc = lane & 31;
    if (n >= NN) return;
    int i0 = rowptr[n], end = rowptr[n + 1];
    float ax = 0.f, ay = 0.f;
    for (int i = i0; i < end; i += 2) {
        int idx = i + half;
        int2 e = (idx < end) ? csr[idx] : make_int2(0, 0);
        unsigned v = *(const unsigned*)&h2b[(size_t)e.x * DOUT + lc * 2];
        float w = __int_as_float(e.y);
        ax = fmaf(w, bflo(v), ax);
        ay = fmaf(w, bfhi(v), ay);
    }
    // combine the two half-wave partials (lanes l and l+32 hold the same col pair)
    ax += __shfl_xor(ax, 32);
    ay += __shfl_xor(ay, 32);
    // log_softmax across 64 cols = 32 lane-pairs x 2 (duplicated in both halves)
    float m = fmaxf(ax, ay);
#pragma unroll
    for (int off = 16; off >= 1; off >>= 1) m = fmaxf(m, __shfl_xor(m, off));
    float s = expf(ax - m) + expf(ay - m);
#pragma unroll
    for (int off = 16; off >= 1; off >>= 1) s += __shfl_xor(s, off);
    float ls = logf(s);
    if (half == 0) {
        float2 o = make_float2(ax - m - ls, ay - m - ls);
        *(float2*)&outp[(size_t)n * DOUT + lc * 2] = o;
    }
}

extern "C" void kernel_launch(void* const* d_in, const int* in_sizes, int n_in,
                              void* d_out, int out_size, void* d_ws, size_t ws_size,
                              hipStream_t stream) {
    const float* x  = (const float*)d_in[0];
    const float* w1 = (const float*)d_in[1];
    const float* w2 = (const float*)d_in[2];
    const int* esrc = (const int*)d_in[3];
    const int* edst = (const int*)d_in[4];
    const float* ew = (const float*)d_in[5];
    float* out = (float*)d_out;

    char* ws = (char*)d_ws;
    size_t off = 0;
    auto alloc = [&](size_t bytes) {
        void* p = ws + off;
        off = (off + bytes + 255) & ~(size_t)255;
        return p;
    };
    bf16_t* h1b    = (bf16_t*)alloc((size_t)NN * DH * 2);     // 25.6 MB
    bf16_t* aggb   = (bf16_t*)alloc((size_t)NN * DH * 2);     // 25.6 MB
    bf16_t* h2b    = (bf16_t*)alloc((size_t)NN * DOUT * 2);   // 12.8 MB
    bf16_t* w1b    = (bf16_t*)alloc((size_t)DH * DIN * 2);
    bf16_t* w2b    = (bf16_t*)alloc((size_t)DOUT * DH * 2);
    int2*   csr    = (int2*)alloc((size_t)NE * 8);            // 12.8 MB
    int*    rowptr = (int*)alloc((size_t)(NN + 1) * 4);
    int*    cursor = (int*)alloc((size_t)NN * 4);
    int*    deg    = (int*)alloc((size_t)NN * 4);
    int*    csum   = (int*)alloc((size_t)NCH * 4);
    int*    cbase  = (int*)alloc((size_t)NCH * 4);

    // 0. weights -> bf16
    convert_w_kernel<<<(DH * DIN + 255) / 256, 256, 0, stream>>>(w1, w2, w1b, w2b);
    // 1. h1b = bf16(x @ w1^T)   (MFMA)
    gemm1_mfma<<<(NN + 127) / 128, 256, 0, stream>>>(x, w1b, h1b);
    // 2. CSR build (bucket sort by dst)
    hipMemsetAsync(deg, 0, (size_t)NN * 4, stream);
    hist_kernel<<<(NE + 255) / 256, 256, 0, stream>>>(edst, deg);
    chunksum_kernel<<<NCH, 256, 0, stream>>>(deg, csum);
    scanchunks_kernel<<<1, 512, 0, stream>>>(csum, cbase, rowptr);
    scanwrite_kernel<<<NCH, 256, 0, stream>>>(deg, cbase, rowptr, cursor);
    scatter_kernel<<<(NE + 255) / 256, 256, 0, stream>>>(esrc, edst, ew, cursor, csr);
    // 3. aggb = relu(gather-SpMM(h1b))
    spmm128_kernel<<<(NN + 3) / 4, 256, 0, stream>>>(csr, rowptr, h1b, aggb);
    // 4. h2b = aggb @ w2^T   (MFMA)
    gemm2_mfma<<<(NN + 127) / 128, 256, 0, stream>>>(aggb, w2b, h2b);
    // 5. out = log_softmax(gather-SpMM(h2b))
    spmm64_ls_kernel<<<(NN + 3) / 4, 256, 0, stream>>>(csr, rowptr, h2b, out);
}

// Round 4
// 434.413 us; speedup vs baseline: 9.9400x; 1.1239x over previous
//
#include <hip/hip_runtime.h>
#include <hip/hip_bf16.h>

#define NN 100000
#define NE 1600000
#define DIN 512
#define DH 128
#define DOUT 64

#define BSH 9                    // bucket = dst >> 9  (512 nodes per bucket)
#define NB ((NN + 511) / 512)    // 196 buckets
#define P1B 512                  // edge-partition blocks for count/write phases
#define EPB ((NE + P1B - 1) / P1B)  // 3125 edges per partition

typedef __bf16 bf16_t;
typedef __bf16 bf16x8 __attribute__((ext_vector_type(8)));
typedef float f32x4 __attribute__((ext_vector_type(4)));

__device__ __forceinline__ float bflo(unsigned v) { return __int_as_float(v << 16); }
__device__ __forceinline__ float bfhi(unsigned v) { return __int_as_float(v & 0xffff0000u); }
__device__ __forceinline__ unsigned packbf2(float a, float b) {
    unsigned short ua = __builtin_bit_cast(unsigned short, (bf16_t)a);
    unsigned short ub = __builtin_bit_cast(unsigned short, (bf16_t)b);
    return (unsigned)ua | ((unsigned)ub << 16);
}

// ---------------- weight conversion: w1 -> bf16, w2 -> packed-transposed [k2][c] ----------------
__global__ __launch_bounds__(256) void convert_w_kernel(const float* __restrict__ w1,
                                                        const float* __restrict__ w2,
                                                        bf16_t* __restrict__ w1b,
                                                        unsigned* __restrict__ w2tp) {
    int i = blockIdx.x * 256 + threadIdx.x;
    if (i < DH * DIN) w1b[i] = (bf16_t)w1[i];
    if (i < (DH / 2) * DOUT) {
        int k2 = i >> 6, c = i & 63;
        w2tp[i] = packbf2(w2[c * DH + 2 * k2], w2[c * DH + 2 * k2 + 1]);
    }
}

// ---------------- GEMM1: h1b[N,128] = bf16(x) @ bf16(w1)^T, MFMA, no LDS ----------------
__global__ __launch_bounds__(256) void gemm1_mfma(const float* __restrict__ x,
                                                  const bf16_t* __restrict__ w1b,
                                                  bf16_t* __restrict__ h1b) {
    const int t = threadIdx.x;
    const int wv = t >> 6, lane = t & 63;
    const int fr = lane & 15, fq = lane >> 4;
    const int rbase = blockIdx.x * 128 + wv * 32;

    f32x4 acc[2][8];
#pragma unroll
    for (int m = 0; m < 2; m++)
#pragma unroll
        for (int n = 0; n < 8; n++) acc[m][n] = (f32x4)0.f;

    int r0 = rbase + fr;
    int r1 = rbase + 16 + fr;
    int r0c = r0 < NN ? r0 : NN - 1;
    int r1c = r1 < NN ? r1 : NN - 1;
    const float*  pa0 = x + (size_t)r0c * DIN + fq * 8;
    const float*  pa1 = x + (size_t)r1c * DIN + fq * 8;
    const bf16_t* pb  = w1b + (size_t)fr * DIN + fq * 8;

    for (int kk = 0; kk < DIN / 32; kk++) {
        float4 a0l = *(const float4*)(pa0);
        float4 a0h = *(const float4*)(pa0 + 4);
        float4 a1l = *(const float4*)(pa1);
        float4 a1h = *(const float4*)(pa1 + 4);
        bf16x8 af0, af1;
        af0[0] = (bf16_t)a0l.x; af0[1] = (bf16_t)a0l.y; af0[2] = (bf16_t)a0l.z; af0[3] = (bf16_t)a0l.w;
        af0[4] = (bf16_t)a0h.x; af0[5] = (bf16_t)a0h.y; af0[6] = (bf16_t)a0h.z; af0[7] = (bf16_t)a0h.w;
        af1[0] = (bf16_t)a1l.x; af1[1] = (bf16_t)a1l.y; af1[2] = (bf16_t)a1l.z; af1[3] = (bf16_t)a1l.w;
        af1[4] = (bf16_t)a1h.x; af1[5] = (bf16_t)a1h.y; af1[6] = (bf16_t)a1h.z; af1[7] = (bf16_t)a1h.w;

        bf16x8 bfr[8];
#pragma unroll
        for (int n = 0; n < 8; n++)
            bfr[n] = *(const bf16x8*)(pb + (size_t)n * 16 * DIN);
#pragma unroll
        for (int n = 0; n < 8; n++) {
            acc[0][n] = __builtin_amdgcn_mfma_f32_16x16x32_bf16(af0, bfr[n], acc[0][n], 0, 0, 0);
            acc[1][n] = __builtin_amdgcn_mfma_f32_16x16x32_bf16(af1, bfr[n], acc[1][n], 0, 0, 0);
        }
        pa0 += 32; pa1 += 32; pb += 32;
    }
#pragma unroll
    for (int m = 0; m < 2; m++)
#pragma unroll
        for (int j = 0; j < 4; j++) {
            int row = rbase + m * 16 + fq * 4 + j;
            if (row < NN) {
#pragma unroll
                for (int n = 0; n < 8; n++)
                    h1b[(size_t)row * DH + n * 16 + fr] = (bf16_t)acc[m][n][j];
            }
        }
}

// ================= CSR build: two-level counting sort =================
// P1: per-(edge-block, bucket) counts via LDS histogram
__global__ __launch_bounds__(256) void p1_count(const int* __restrict__ edst,
                                                int* __restrict__ counts) {  // [P1B][256]
    __shared__ int h[NB];
    int blk = blockIdx.x, t = threadIdx.x;
    for (int i = t; i < NB; i += 256) h[i] = 0;
    __syncthreads();
    int e0 = blk * EPB, e1 = min(e0 + EPB, NE);
    for (int e = e0 + t; e < e1; e += 256) atomicAdd(&h[edst[e] >> BSH], 1);
    __syncthreads();
    for (int i = t; i < NB; i += 256) counts[blk * 256 + i] = h[i];
}

// P2: per-bucket exclusive scan over the 512 edge-blocks
__global__ __launch_bounds__(256) void p2_scanblocks(const int* __restrict__ counts,
                                                     int* __restrict__ blockoffs,  // [P1B][256]
                                                     int* __restrict__ btotal) {   // [NB]
    __shared__ int s[512];
    int b = blockIdx.x, t = threadIdx.x;
    int c0 = counts[t * 256 + b];
    int c1 = counts[(t + 256) * 256 + b];
    s[t] = c0; s[t + 256] = c1;
    __syncthreads();
    for (int off = 1; off < 512; off <<= 1) {
        int v0 = (t >= off) ? s[t - off] : 0;
        int v1 = (t + 256 >= off) ? s[t + 256 - off] : 0;
        __syncthreads();
        s[t] += v0; s[t + 256] += v1;
        __syncthreads();
    }
    blockoffs[t * 256 + b] = s[t] - c0;                 // exclusive
    blockoffs[(t + 256) * 256 + b] = s[t + 256] - c1;
    if (t == 0) btotal[b] = s[511];
}

// P3: exclusive scan over bucket totals -> bucket bases; rowptr[NN]=NE
__global__ __launch_bounds__(256) void p3_scanbuckets(const int* __restrict__ btotal,
                                                      int* __restrict__ bbase,
                                                      int* __restrict__ rowptr) {
    __shared__ int s[256];
    int t = threadIdx.x;
    int self = (t < NB) ? btotal[t] : 0;
    s[t] = self;
    __syncthreads();
    for (int off = 1; off < 256; off <<= 1) {
        int v = (t >= off) ? s[t - off] : 0;
        __syncthreads();
        s[t] += v;
        __syncthreads();
    }
    if (t < NB) bbase[t] = s[t] - self;
    if (t == 0) rowptr[NN] = NE;
}

// P4: write edges grouped by bucket (each block owns a contiguous run per bucket)
__global__ __launch_bounds__(256) void p4_bucketwrite(const int* __restrict__ esrc,
                                                      const int* __restrict__ edst,
                                                      const float* __restrict__ ew,
                                                      const int* __restrict__ blockoffs,
                                                      const int* __restrict__ bbase,
                                                      int2* __restrict__ bsrcw,
                                                      unsigned short* __restrict__ bdst16) {
    __shared__ int cur[NB];
    int blk = blockIdx.x, t = threadIdx.x;
    for (int i = t; i < NB; i += 256) cur[i] = bbase[i] + blockoffs[blk * 256 + i];
    __syncthreads();
    int e0 = blk * EPB, e1 = min(e0 + EPB, NE);
    for (int e = e0 + t; e < e1; e += 256) {
        int d = edst[e];
        int b = d >> BSH;
        int pos = atomicAdd(&cur[b], 1);
        bsrcw[pos] = make_int2(esrc[e], __float_as_int(ew[e]));
        bdst16[pos] = (unsigned short)(d & 511);
    }
}

// P5: in-bucket 512-bin counting sort -> final CSR + rowptr
__global__ __launch_bounds__(256) void p5_bucketsort(const int2* __restrict__ bsrcw,
                                                     const unsigned short* __restrict__ bdst16,
                                                     const int* __restrict__ bbase,
                                                     const int* __restrict__ btotal,
                                                     int2* __restrict__ csr,
                                                     int* __restrict__ rowptr) {
    __shared__ int cnt[512];
    __shared__ int curs[512];
    __shared__ int sc[256];
    int b = blockIdx.x, t = threadIdx.x;
    int base = bbase[b], n = btotal[b];
    int node0 = b << BSH;
    cnt[t] = 0; cnt[t + 256] = 0;
    __syncthreads();
    for (int i = t; i < n; i += 256) atomicAdd(&cnt[bdst16[base + i]], 1);
    __syncthreads();
    int c0 = cnt[2 * t], c1 = cnt[2 * t + 1];
    sc[t] = c0 + c1;
    __syncthreads();
    for (int off = 1; off < 256; off <<= 1) {
        int v = (t >= off) ? sc[t - off] : 0;
        __syncthreads();
        sc[t] += v;
        __syncthreads();
    }
    int e0 = (t > 0) ? sc[t - 1] : 0;    // exclusive base for pair (2t, 2t+1)
    curs[2 * t] = e0;
    curs[2 * t + 1] = e0 + c0;
    int n0 = node0 + 2 * t, n1 = node0 + 2 * t + 1;
    if (n0 < NN) rowptr[n0] = base + e0;
    if (n1 < NN) rowptr[n1] = base + e0 + c0;
    __syncthreads();
    for (int i = t; i < n; i += 256) {
        unsigned short d = bdst16[base + i];
        int2 sw = bsrcw[base + i];
        int p = atomicAdd(&curs[d], 1);
        csr[base + p] = sw;
    }
}

// ---------------- fused: spmm128 (gather) + relu + gemm2 matvec -> h2b ----------------
__global__ __launch_bounds__(256) void spmm1_fused(const int2* __restrict__ csr,
                                                   const int* __restrict__ rowptr,
                                                   const bf16_t* __restrict__ h1b,
                                                   const unsigned* __restrict__ w2tp,
                                                   bf16_t* __restrict__ h2b) {
    __shared__ unsigned w2s[64 * 64];   // [k2][c], 16 KB, conflict-free column reads
    __shared__ float aggs[4][130];
    int t = threadIdx.x;
    for (int i = t; i < 4096; i += 256) w2s[i] = w2tp[i];
    __syncthreads();

    int wv = t >> 6, lane = t & 63;
    int n = blockIdx.x * 4 + wv;        // NN % 4 == 0 -> always valid
    int i = rowptr[n], end = rowptr[n + 1];
    float ax = 0.f, ay = 0.f;
    for (; i + 1 < end; i += 2) {
        int2 e0 = csr[i];
        int2 e1 = csr[i + 1];
        unsigned v0 = *(const unsigned*)&h1b[(size_t)e0.x * DH + lane * 2];
        unsigned v1 = *(const unsigned*)&h1b[(size_t)e1.x * DH + lane * 2];
        float w0 = __int_as_float(e0.y), w1 = __int_as_float(e1.y);
        ax = fmaf(w0, bflo(v0), ax); ay = fmaf(w0, bfhi(v0), ay);
        ax = fmaf(w1, bflo(v1), ax); ay = fmaf(w1, bfhi(v1), ay);
    }
    if (i < end) {
        int2 e0 = csr[i];
        unsigned v0 = *(const unsigned*)&h1b[(size_t)e0.x * DH + lane * 2];
        float w0 = __int_as_float(e0.y);
        ax = fmaf(w0, bflo(v0), ax); ay = fmaf(w0, bfhi(v0), ay);
    }
    ax = fmaxf(ax, 0.f); ay = fmaxf(ay, 0.f);     // relu
    aggs[wv][lane * 2] = ax; aggs[wv][lane * 2 + 1] = ay;
    // in-wave matvec: h2[n][c] = sum_k agg[k] * w2[c][k], c = lane
    float acc = 0.f;
    const unsigned* wcol = w2s + lane;
#pragma unroll 8
    for (int k2 = 0; k2 < 64; k2++) {
        float2 a2 = *(const float2*)&aggs[wv][2 * k2];   // broadcast
        unsigned wp = wcol[k2 * 64];
        acc = fmaf(a2.x, bflo(wp), acc);
        acc = fmaf(a2.y, bfhi(wp), acc);
    }
    h2b[(size_t)n * DOUT + lane] = (bf16_t)acc;
}

// ---------------- SpMM-CSR d=64 + fused log_softmax ----------------
__global__ __launch_bounds__(256) void spmm64_ls_kernel(const int2* __restrict__ csr,
                                                        const int* __restrict__ rowptr,
                                                        const bf16_t* __restrict__ h2b,
                                                        float* __restrict__ outp) {
    int n = blockIdx.x * 4 + (threadIdx.x >> 6);
    int lane = threadIdx.x & 63;
    int half = lane >> 5, lc = lane & 31;
    if (n >= NN) return;
    int i0 = rowptr[n], end = rowptr[n + 1];
    float ax = 0.f, ay = 0.f;
    for (int i = i0; i < end; i += 2) {
        int idx = i + half;
        int2 e = (idx < end) ? csr[idx] : make_int2(0, 0);
        unsigned v = *(const unsigned*)&h2b[(size_t)e.x * DOUT + lc * 2];
        float w = __int_as_float(e.y);
        ax = fmaf(w, bflo(v), ax);
        ay = fmaf(w, bfhi(v), ay);
    }
    ax += __shfl_xor(ax, 32);
    ay += __shfl_xor(ay, 32);
    float m = fmaxf(ax, ay);
#pragma unroll
    for (int off = 16; off >= 1; off >>= 1) m = fmaxf(m, __shfl_xor(m, off));
    float s = expf(ax - m) + expf(ay - m);
#pragma unroll
    for (int off = 16; off >= 1; off >>= 1) s += __shfl_xor(s, off);
    float ls = logf(s);
    if (half == 0) {
        float2 o = make_float2(ax - m - ls, ay - m - ls);
        *(float2*)&outp[(size_t)n * DOUT + lc * 2] = o;
    }
}

extern "C" void kernel_launch(void* const* d_in, const int* in_sizes, int n_in,
                              void* d_out, int out_size, void* d_ws, size_t ws_size,
                              hipStream_t stream) {
    const float* x  = (const float*)d_in[0];
    const float* w1 = (const float*)d_in[1];
    const float* w2 = (const float*)d_in[2];
    const int* esrc = (const int*)d_in[3];
    const int* edst = (const int*)d_in[4];
    const float* ew = (const float*)d_in[5];
    float* out = (float*)d_out;

    char* ws = (char*)d_ws;
    size_t off = 0;
    auto alloc = [&](size_t bytes) {
        void* p = ws + off;
        off = (off + bytes + 255) & ~(size_t)255;
        return p;
    };
    bf16_t* h1b      = (bf16_t*)alloc((size_t)NN * DH * 2);      // 25.6 MB
    bf16_t* h2b      = (bf16_t*)alloc((size_t)NN * DOUT * 2);    // 12.8 MB
    bf16_t* w1b      = (bf16_t*)alloc((size_t)DH * DIN * 2);
    unsigned* w2tp   = (unsigned*)alloc((size_t)(DH / 2) * DOUT * 4);
    int2*   csr      = (int2*)alloc((size_t)NE * 8);             // 12.8 MB
    int2*   bsrcw    = (int2*)alloc((size_t)NE * 8);             // 12.8 MB
    unsigned short* bdst16 = (unsigned short*)alloc((size_t)NE * 2);  // 3.2 MB
    int*    rowptr   = (int*)alloc((size_t)(NN + 1) * 4);
    int*    counts   = (int*)alloc((size_t)P1B * 256 * 4);       // 512 KB
    int*    blockoffs= (int*)alloc((size_t)P1B * 256 * 4);       // 512 KB
    int*    btotal   = (int*)alloc((size_t)256 * 4);
    int*    bbase    = (int*)alloc((size_t)256 * 4);

    // 0. weights
    convert_w_kernel<<<(DH * DIN + 255) / 256, 256, 0, stream>>>(w1, w2, w1b, w2tp);
    // 1. h1b = bf16(x @ w1^T)
    gemm1_mfma<<<(NN + 127) / 128, 256, 0, stream>>>(x, w1b, h1b);
    // 2. CSR build (two-level counting sort, no global atomics, L2-local writes)
    p1_count<<<P1B, 256, 0, stream>>>(edst, counts);
    p2_scanblocks<<<NB, 256, 0, stream>>>(counts, blockoffs, btotal);
    p3_scanbuckets<<<1, 256, 0, stream>>>(btotal, bbase, rowptr);
    p4_bucketwrite<<<P1B, 256, 0, stream>>>(esrc, edst, ew, blockoffs, bbase, bsrcw, bdst16);
    p5_bucketsort<<<NB, 256, 0, stream>>>(bsrcw, bdst16, bbase, btotal, csr, rowptr);
    // 3+4. h2b = relu(SpMM(h1b)) @ w2^T   (fused)
    spmm1_fused<<<NN / 4, 256, 0, stream>>>(csr, rowptr, h1b, w2tp, h2b);
    // 5. out = log_softmax(SpMM(h2b))
    spmm64_ls_kernel<<<(NN + 3) / 4, 256, 0, stream>>>(csr, rowptr, h2b, out);
}

// Round 5
// 347.314 us; speedup vs baseline: 12.4328x; 1.2508x over previous
//
#include <hip/hip_runtime.h>
#include <hip/hip_bf16.h>

#define NN 100000
#define NE 1600000
#define DIN 512
#define DH 128
#define DOUT 64

#define BSH 9                    // bucket = dst >> 9  (512 nodes per bucket)
#define NB ((NN + 511) / 512)    // 196 buckets
#define P1B 512                  // edge-partition blocks for count/write phases
#define EPB ((NE + P1B - 1) / P1B)  // 3125 edges per partition

typedef __bf16 bf16_t;
typedef __bf16 bf16x8 __attribute__((ext_vector_type(8)));
typedef float f32x4 __attribute__((ext_vector_type(4)));

__device__ __forceinline__ float bflo(unsigned v) { return __int_as_float(v << 16); }
__device__ __forceinline__ float bfhi(unsigned v) { return __int_as_float(v & 0xffff0000u); }
__device__ __forceinline__ unsigned packbf2(float a, float b) {
    unsigned short ua = __builtin_bit_cast(unsigned short, (bf16_t)a);
    unsigned short ub = __builtin_bit_cast(unsigned short, (bf16_t)b);
    return (unsigned)ua | ((unsigned)ub << 16);
}

// ---------------- weight conversion: w1,w2 -> bf16 ----------------
__global__ __launch_bounds__(256) void convert_w_kernel(const float* __restrict__ w1,
                                                        const float* __restrict__ w2,
                                                        bf16_t* __restrict__ w1b,
                                                        bf16_t* __restrict__ w2b) {
    int i = blockIdx.x * 256 + threadIdx.x;
    if (i < DH * DIN) w1b[i] = (bf16_t)w1[i];
    if (i < DOUT * DH) w2b[i] = (bf16_t)w2[i];
}

// ---------------- GEMM1: h1b[N,128] = bf16(x) @ bf16(w1)^T, MFMA, no LDS ----------------
__global__ __launch_bounds__(256) void gemm1_mfma(const float* __restrict__ x,
                                                  const bf16_t* __restrict__ w1b,
                                                  bf16_t* __restrict__ h1b) {
    const int t = threadIdx.x;
    const int wv = t >> 6, lane = t & 63;
    const int fr = lane & 15, fq = lane >> 4;
    const int rbase = blockIdx.x * 128 + wv * 32;

    f32x4 acc[2][8];
#pragma unroll
    for (int m = 0; m < 2; m++)
#pragma unroll
        for (int n = 0; n < 8; n++) acc[m][n] = (f32x4)0.f;

    int r0 = rbase + fr;
    int r1 = rbase + 16 + fr;
    int r0c = r0 < NN ? r0 : NN - 1;
    int r1c = r1 < NN ? r1 : NN - 1;
    const float*  pa0 = x + (size_t)r0c * DIN + fq * 8;
    const float*  pa1 = x + (size_t)r1c * DIN + fq * 8;
    const bf16_t* pb  = w1b + (size_t)fr * DIN + fq * 8;

    for (int kk = 0; kk < DIN / 32; kk++) {
        float4 a0l = *(const float4*)(pa0);
        float4 a0h = *(const float4*)(pa0 + 4);
        float4 a1l = *(const float4*)(pa1);
        float4 a1h = *(const float4*)(pa1 + 4);
        bf16x8 af0, af1;
        af0[0] = (bf16_t)a0l.x; af0[1] = (bf16_t)a0l.y; af0[2] = (bf16_t)a0l.z; af0[3] = (bf16_t)a0l.w;
        af0[4] = (bf16_t)a0h.x; af0[5] = (bf16_t)a0h.y; af0[6] = (bf16_t)a0h.z; af0[7] = (bf16_t)a0h.w;
        af1[0] = (bf16_t)a1l.x; af1[1] = (bf16_t)a1l.y; af1[2] = (bf16_t)a1l.z; af1[3] = (bf16_t)a1l.w;
        af1[4] = (bf16_t)a1h.x; af1[5] = (bf16_t)a1h.y; af1[6] = (bf16_t)a1h.z; af1[7] = (bf16_t)a1h.w;

        bf16x8 bfr[8];
#pragma unroll
        for (int n = 0; n < 8; n++)
            bfr[n] = *(const bf16x8*)(pb + (size_t)n * 16 * DIN);
#pragma unroll
        for (int n = 0; n < 8; n++) {
            acc[0][n] = __builtin_amdgcn_mfma_f32_16x16x32_bf16(af0, bfr[n], acc[0][n], 0, 0, 0);
            acc[1][n] = __builtin_amdgcn_mfma_f32_16x16x32_bf16(af1, bfr[n], acc[1][n], 0, 0, 0);
        }
        pa0 += 32; pa1 += 32; pb += 32;
    }
#pragma unroll
    for (int m = 0; m < 2; m++)
#pragma unroll
        for (int j = 0; j < 4; j++) {
            int row = rbase + m * 16 + fq * 4 + j;
            if (row < NN) {
#pragma unroll
                for (int n = 0; n < 8; n++)
                    h1b[(size_t)row * DH + n * 16 + fr] = (bf16_t)acc[m][n][j];
            }
        }
}

// ================= CSR build: two-level counting sort =================
__global__ __launch_bounds__(256) void p1_count(const int* __restrict__ edst,
                                                int* __restrict__ counts) {  // [P1B][256]
    __shared__ int h[NB];
    int blk = blockIdx.x, t = threadIdx.x;
    for (int i = t; i < NB; i += 256) h[i] = 0;
    __syncthreads();
    int e0 = blk * EPB, e1 = min(e0 + EPB, NE);
    for (int e = e0 + t; e < e1; e += 256) atomicAdd(&h[edst[e] >> BSH], 1);
    __syncthreads();
    for (int i = t; i < NB; i += 256) counts[blk * 256 + i] = h[i];
}

__global__ __launch_bounds__(256) void p2_scanblocks(const int* __restrict__ counts,
                                                     int* __restrict__ blockoffs,  // [P1B][256]
                                                     int* __restrict__ btotal) {   // [NB]
    __shared__ int s[512];
    int b = blockIdx.x, t = threadIdx.x;
    int c0 = counts[t * 256 + b];
    int c1 = counts[(t + 256) * 256 + b];
    s[t] = c0; s[t + 256] = c1;
    __syncthreads();
    for (int off = 1; off < 512; off <<= 1) {
        int v0 = (t >= off) ? s[t - off] : 0;
        int v1 = (t + 256 >= off) ? s[t + 256 - off] : 0;
        __syncthreads();
        s[t] += v0; s[t + 256] += v1;
        __syncthreads();
    }
    blockoffs[t * 256 + b] = s[t] - c0;
    blockoffs[(t + 256) * 256 + b] = s[t + 256] - c1;
    if (t == 0) btotal[b] = s[511];
}

__global__ __launch_bounds__(256) void p3_scanbuckets(const int* __restrict__ btotal,
                                                      int* __restrict__ bbase,
                                                      int* __restrict__ rowptr) {
    __shared__ int s[256];
    int t = threadIdx.x;
    int self = (t < NB) ? btotal[t] : 0;
    s[t] = self;
    __syncthreads();
    for (int off = 1; off < 256; off <<= 1) {
        int v = (t >= off) ? s[t - off] : 0;
        __syncthreads();
        s[t] += v;
        __syncthreads();
    }
    if (t < NB) bbase[t] = s[t] - self;
    if (t == 0) rowptr[NN] = NE;
}

__global__ __launch_bounds__(256) void p4_bucketwrite(const int* __restrict__ esrc,
                                                      const int* __restrict__ edst,
                                                      const float* __restrict__ ew,
                                                      const int* __restrict__ blockoffs,
                                                      const int* __restrict__ bbase,
                                                      int2* __restrict__ bsrcw,
                                                      unsigned short* __restrict__ bdst16) {
    __shared__ int cur[NB];
    int blk = blockIdx.x, t = threadIdx.x;
    for (int i = t; i < NB; i += 256) cur[i] = bbase[i] + blockoffs[blk * 256 + i];
    __syncthreads();
    int e0 = blk * EPB, e1 = min(e0 + EPB, NE);
    for (int e = e0 + t; e < e1; e += 256) {
        int d = edst[e];
        int b = d >> BSH;
        int pos = atomicAdd(&cur[b], 1);
        bsrcw[pos] = make_int2(esrc[e], __float_as_int(ew[e]));
        bdst16[pos] = (unsigned short)(d & 511);
    }
}

__global__ __launch_bounds__(256) void p5_bucketsort(const int2* __restrict__ bsrcw,
                                                     const unsigned short* __restrict__ bdst16,
                                                     const int* __restrict__ bbase,
                                                     const int* __restrict__ btotal,
                                                     int2* __restrict__ csr,
                                                     int* __restrict__ rowptr) {
    __shared__ int cnt[512];
    __shared__ int curs[512];
    __shared__ int sc[256];
    int b = blockIdx.x, t = threadIdx.x;
    int base = bbase[b], n = btotal[b];
    int node0 = b << BSH;
    cnt[t] = 0; cnt[t + 256] = 0;
    __syncthreads();
    for (int i = t; i < n; i += 256) atomicAdd(&cnt[bdst16[base + i]], 1);
    __syncthreads();
    int c0 = cnt[2 * t], c1 = cnt[2 * t + 1];
    sc[t] = c0 + c1;
    __syncthreads();
    for (int off = 1; off < 256; off <<= 1) {
        int v = (t >= off) ? sc[t - off] : 0;
        __syncthreads();
        sc[t] += v;
        __syncthreads();
    }
    int e0 = (t > 0) ? sc[t - 1] : 0;
    curs[2 * t] = e0;
    curs[2 * t + 1] = e0 + c0;
    int n0 = node0 + 2 * t, n1 = node0 + 2 * t + 1;
    if (n0 < NN) rowptr[n0] = base + e0;
    if (n1 < NN) rowptr[n1] = base + e0 + c0;
    __syncthreads();
    for (int i = t; i < n; i += 256) {
        unsigned short d = bdst16[base + i];
        int2 sw = bsrcw[base + i];
        int p = atomicAdd(&curs[d], 1);
        csr[base + p] = sw;
    }
}

// ---------------- fused: spmm128 gather (4-deep ILP) + relu + MFMA matvec -> h2b ----------------
// Block = 16 nodes (4 per wave). Phase 1: each wave gathers+accumulates 4 rows, packs
// relu'd bf16 rows into LDS. Phase 2: each wave computes one 16-col tile of agg@w2^T via MFMA.
__global__ __launch_bounds__(256) void spmm1_fused(const int2* __restrict__ csr,
                                                   const int* __restrict__ rowptr,
                                                   const bf16_t* __restrict__ h1b,
                                                   const bf16_t* __restrict__ w2b,
                                                   bf16_t* __restrict__ h2b) {
    __shared__ unsigned aggs[16][68];   // [node][k-pair], stride 68 dwords (16B-aligned rows)
    const int t = threadIdx.x;
    const int wv = t >> 6, lane = t & 63;
    const int nb = blockIdx.x * 16;     // NN % 16 == 0

#pragma unroll
    for (int q = 0; q < 4; q++) {
        int n = nb + wv * 4 + q;
        int st = rowptr[n], end = rowptr[n + 1];
        float ax = 0.f, ay = 0.f;
        for (int i = st; i < end; i += 4) {
            bool b1 = (i + 1 < end), b2 = (i + 2 < end), b3 = (i + 3 < end);
            int2 e0 = csr[i];
            int2 e1 = csr[b1 ? i + 1 : st];
            int2 e2 = csr[b2 ? i + 2 : st];
            int2 e3 = csr[b3 ? i + 3 : st];
            float w0 = __int_as_float(e0.y);
            float w1 = b1 ? __int_as_float(e1.y) : 0.f;
            float w2 = b2 ? __int_as_float(e2.y) : 0.f;
            float w3 = b3 ? __int_as_float(e3.y) : 0.f;
            unsigned v0 = *(const unsigned*)&h1b[(size_t)e0.x * DH + lane * 2];
            unsigned v1 = *(const unsigned*)&h1b[(size_t)e1.x * DH + lane * 2];
            unsigned v2 = *(const unsigned*)&h1b[(size_t)e2.x * DH + lane * 2];
            unsigned v3 = *(const unsigned*)&h1b[(size_t)e3.x * DH + lane * 2];
            ax = fmaf(w0, bflo(v0), ax); ay = fmaf(w0, bfhi(v0), ay);
            ax = fmaf(w1, bflo(v1), ax); ay = fmaf(w1, bfhi(v1), ay);
            ax = fmaf(w2, bflo(v2), ax); ay = fmaf(w2, bfhi(v2), ay);
            ax = fmaf(w3, bflo(v3), ax); ay = fmaf(w3, bfhi(v3), ay);
        }
        ax = fmaxf(ax, 0.f); ay = fmaxf(ay, 0.f);     // relu
        aggs[wv * 4 + q][lane] = packbf2(ax, ay);
    }
    __syncthreads();

    // MFMA: A = aggs[16][128] (LDS), B = w2 rows wv*16..wv*16+15 (L2), C = 16x16
    const int fr = lane & 15, fq = lane >> 4;
    f32x4 acc = (f32x4)0.f;
    const bf16_t* pb = w2b + (size_t)(wv * 16 + fr) * DH + fq * 8;
    const bf16_t* arow = (const bf16_t*)aggs[fr];
#pragma unroll
    for (int kk = 0; kk < 4; kk++) {
        bf16x8 af = *(const bf16x8*)&arow[kk * 32 + fq * 8];
        bf16x8 bf = *(const bf16x8*)(pb + kk * 32);
        acc = __builtin_amdgcn_mfma_f32_16x16x32_bf16(af, bf, acc, 0, 0, 0);
    }
#pragma unroll
    for (int j = 0; j < 4; j++) {
        int node = nb + fq * 4 + j;
        h2b[(size_t)node * DOUT + wv * 16 + fr] = (bf16_t)acc[j];
    }
}

// ---------------- SpMM-CSR d=64 + fused log_softmax (4 edges in flight) ----------------
__global__ __launch_bounds__(256) void spmm64_ls_kernel(const int2* __restrict__ csr,
                                                        const int* __restrict__ rowptr,
                                                        const bf16_t* __restrict__ h2b,
                                                        float* __restrict__ outp) {
    int n = blockIdx.x * 4 + (threadIdx.x >> 6);
    int lane = threadIdx.x & 63;
    int half = lane >> 5, lc = lane & 31;
    if (n >= NN) return;
    int st = rowptr[n], end = rowptr[n + 1];
    float ax = 0.f, ay = 0.f;
    for (int i = st; i < end; i += 4) {
        int ia = i + half * 2;
        bool b0 = (ia < end), b1 = (ia + 1 < end);
        int2 e0 = csr[b0 ? ia : st];
        int2 e1 = csr[b1 ? ia + 1 : st];
        float w0 = b0 ? __int_as_float(e0.y) : 0.f;
        float w1 = b1 ? __int_as_float(e1.y) : 0.f;
        unsigned v0 = *(const unsigned*)&h2b[(size_t)e0.x * DOUT + lc * 2];
        unsigned v1 = *(const unsigned*)&h2b[(size_t)e1.x * DOUT + lc * 2];
        ax = fmaf(w0, bflo(v0), ax); ay = fmaf(w0, bfhi(v0), ay);
        ax = fmaf(w1, bflo(v1), ax); ay = fmaf(w1, bfhi(v1), ay);
    }
    ax += __shfl_xor(ax, 32);
    ay += __shfl_xor(ay, 32);
    float m = fmaxf(ax, ay);
#pragma unroll
    for (int off = 16; off >= 1; off >>= 1) m = fmaxf(m, __shfl_xor(m, off));
    float s = expf(ax - m) + expf(ay - m);
#pragma unroll
    for (int off = 16; off >= 1; off >>= 1) s += __shfl_xor(s, off);
    float ls = logf(s);
    if (half == 0) {
        float2 o = make_float2(ax - m - ls, ay - m - ls);
        *(float2*)&outp[(size_t)n * DOUT + lc * 2] = o;
    }
}

extern "C" void kernel_launch(void* const* d_in, const int* in_sizes, int n_in,
                              void* d_out, int out_size, void* d_ws, size_t ws_size,
                              hipStream_t stream) {
    const float* x  = (const float*)d_in[0];
    const float* w1 = (const float*)d_in[1];
    const float* w2 = (const float*)d_in[2];
    const int* esrc = (const int*)d_in[3];
    const int* edst = (const int*)d_in[4];
    const float* ew = (const float*)d_in[5];
    float* out = (float*)d_out;

    char* ws = (char*)d_ws;
    size_t off = 0;
    auto alloc = [&](size_t bytes) {
        void* p = ws + off;
        off = (off + bytes + 255) & ~(size_t)255;
        return p;
    };
    bf16_t* h1b      = (bf16_t*)alloc((size_t)NN * DH * 2);      // 25.6 MB
    bf16_t* h2b      = (bf16_t*)alloc((size_t)NN * DOUT * 2);    // 12.8 MB
    bf16_t* w1b      = (bf16_t*)alloc((size_t)DH * DIN * 2);
    bf16_t* w2b      = (bf16_t*)alloc((size_t)DOUT * DH * 2);
    int2*   csr      = (int2*)alloc((size_t)(NE + 8) * 8);       // 12.8 MB
    int2*   bsrcw    = (int2*)alloc((size_t)NE * 8);             // 12.8 MB
    unsigned short* bdst16 = (unsigned short*)alloc((size_t)NE * 2);
    int*    rowptr   = (int*)alloc((size_t)(NN + 1) * 4);
    int*    counts   = (int*)alloc((size_t)P1B * 256 * 4);
    int*    blockoffs= (int*)alloc((size_t)P1B * 256 * 4);
    int*    btotal   = (int*)alloc((size_t)256 * 4);
    int*    bbase    = (int*)alloc((size_t)256 * 4);

    // 0. weights -> bf16
    convert_w_kernel<<<(DH * DIN + 255) / 256, 256, 0, stream>>>(w1, w2, w1b, w2b);
    // 1. h1b = bf16(x @ w1^T)
    gemm1_mfma<<<(NN + 127) / 128, 256, 0, stream>>>(x, w1b, h1b);
    // 2. CSR build
    p1_count<<<P1B, 256, 0, stream>>>(edst, counts);
    p2_scanblocks<<<NB, 256, 0, stream>>>(counts, blockoffs, btotal);
    p3_scanbuckets<<<1, 256, 0, stream>>>(btotal, bbase, rowptr);
    p4_bucketwrite<<<P1B, 256, 0, stream>>>(esrc, edst, ew, blockoffs, bbase, bsrcw, bdst16);
    p5_bucketsort<<<NB, 256, 0, stream>>>(bsrcw, bdst16, bbase, btotal, csr, rowptr);
    // 3+4. h2b = relu(SpMM(h1b)) @ w2^T   (fused, MFMA epilogue)
    spmm1_fused<<<NN / 16, 256, 0, stream>>>(csr, rowptr, h1b, w2b, h2b);
    // 5. out = log_softmax(SpMM(h2b))
    spmm64_ls_kernel<<<(NN + 3) / 4, 256, 0, stream>>>(csr, rowptr, h2b, out);
}